// Round 1
// baseline (266.990 us; speedup 1.0000x reference)
//
#include <hip/hip_runtime.h>
#include <hip/hip_bf16.h>

#define B_N 8192
#define K_N 256
#define DIM_N 1024

// ---------------- prep1: per-class k -> W1 = D_inv, W2n = -2*c*D_inv, c2[k], dsf[k] ----------------
__global__ __launch_bounds__(256) void gmm_prep1(const float* __restrict__ Dm,
                                                 const float* __restrict__ Cm,
                                                 float* __restrict__ W1,
                                                 float* __restrict__ W2n,
                                                 float* __restrict__ c2,
                                                 float* __restrict__ dsf) {
    const int k = blockIdx.x;
    const int t = threadIdx.x;
    const int d = t * 4;
    const float4 dv = *(const float4*)(Dm + k * DIM_N + d);
    const float4 cv = *(const float4*)(Cm + k * DIM_N + d);
    float dd[4] = {dv.x, dv.y, dv.z, dv.w};
    float cc[4] = {cv.x, cv.y, cv.z, cv.w};
    float o1[4], o2[4];
    float llog = 0.f, lc2 = 0.f;
#pragma unroll
    for (int i = 0; i < 4; ++i) {
        float da = fabsf(dd[i]) + 1e-4f;
        float dinv = 1.0f / da;
        llog += logf(da);
        o1[i] = dinv;
        o2[i] = -2.0f * cc[i] * dinv;
        lc2 += cc[i] * cc[i] * dinv;
    }
    *(float4*)(W1 + k * DIM_N + d) = make_float4(o1[0], o1[1], o1[2], o1[3]);
    *(float4*)(W2n + k * DIM_N + d) = make_float4(o2[0], o2[1], o2[2], o2[3]);
#pragma unroll
    for (int m = 1; m <= 32; m <<= 1) {
        llog += __shfl_xor(llog, m, 64);
        lc2 += __shfl_xor(lc2, m, 64);
    }
    __shared__ float sl[4], sc[4];
    if ((t & 63) == 0) { sl[t >> 6] = llog; sc[t >> 6] = lc2; }
    __syncthreads();
    if (t == 0) {
        float a = sl[0] + sl[1] + sl[2] + sl[3];
        float b = sc[0] + sc[1] + sc[2] + sc[3];
        dsf[k] = -0.5f * a;
        c2[k] = b;
    }
}

// ---------------- prep2: dss[k] = exp(dsf[k] - max_k dsf) ----------------
__global__ __launch_bounds__(256) void gmm_prep2(const float* __restrict__ dsf,
                                                 float* __restrict__ dss) {
    const int t = threadIdx.x;
    const float v = dsf[t];
    float m = v;
#pragma unroll
    for (int msk = 1; msk <= 32; msk <<= 1) m = fmaxf(m, __shfl_xor(m, msk, 64));
    __shared__ float sm[4];
    if ((t & 63) == 0) sm[t >> 6] = m;
    __syncthreads();
    m = fmaxf(fmaxf(sm[0], sm[1]), fmaxf(sm[2], sm[3]));
    dss[t] = expf(v - m);
}

// ---------------- main: fused dist_sq GEMM + weighted row-softmax ----------------
// Block: 32 rows x all 256 classes. 256 threads: tc = tid&31 (class group),
// tr = tid>>5 (row group). Per-thread micro-tile: 4 rows x 8 classes.
__global__ __launch_bounds__(256) void gmm_main(const float* __restrict__ x,
                                                const float* __restrict__ W1,
                                                const float* __restrict__ W2n,
                                                const float* __restrict__ c2g,
                                                const float* __restrict__ dssg,
                                                float* __restrict__ out) {
    __shared__ float2 Wlds[16][256];  // [dk][k] = {D_inv, -2*c*D_inv}  (32 KB)
    __shared__ float xs[16][32];      // [dk][row] = x                  (2 KB)
    __shared__ float xs2[16][32];     // [dk][row] = x^2                (2 KB)

    const int tid = threadIdx.x;
    const int tc = tid & 31;
    const int tr = tid >> 5;
    const int bRow = blockIdx.x * 32;

    float acc[4][8];
#pragma unroll
    for (int i = 0; i < 4; ++i)
#pragma unroll
        for (int j = 0; j < 8; ++j) acc[i][j] = 0.f;

    const int xr = tid >> 2;
    const int xq = tid & 3;

    for (int step = 0; step < 64; ++step) {
        const int d0 = step * 16;
        // ---- issue global loads early (latency overlaps previous compute) ----
        float4 a[4], b[4];
#pragma unroll
        for (int q = 0; q < 4; ++q) {
            a[q] = *(const float4*)(W1 + tid * DIM_N + d0 + q * 4);
            b[q] = *(const float4*)(W2n + tid * DIM_N + d0 + q * 4);
        }
        float4 xv4 = make_float4(0.f, 0.f, 0.f, 0.f);
        if (tid < 128)
            xv4 = *(const float4*)(x + (size_t)(bRow + xr) * DIM_N + d0 + xq * 4);

        __syncthreads();  // previous iteration's compute done reading LDS
        // ---- write LDS ----
#pragma unroll
        for (int q = 0; q < 4; ++q) {
            float av[4] = {a[q].x, a[q].y, a[q].z, a[q].w};
            float bv[4] = {b[q].x, b[q].y, b[q].z, b[q].w};
#pragma unroll
            for (int tt = 0; tt < 4; ++tt)
                Wlds[q * 4 + tt][tid] = make_float2(av[tt], bv[tt]);
        }
        if (tid < 128) {
            float v[4] = {xv4.x, xv4.y, xv4.z, xv4.w};
#pragma unroll
            for (int tt = 0; tt < 4; ++tt) {
                xs[xq * 4 + tt][xr] = v[tt];
                xs2[xq * 4 + tt][xr] = v[tt] * v[tt];
            }
        }
        __syncthreads();
        // ---- compute ----
#pragma unroll
        for (int dk = 0; dk < 16; ++dk) {
            float4 xv = *(const float4*)&xs[dk][tr * 4];
            float4 xw = *(const float4*)&xs2[dk][tr * 4];
            float xvv[4] = {xv.x, xv.y, xv.z, xv.w};
            float xqq[4] = {xw.x, xw.y, xw.z, xw.w};
#pragma unroll
            for (int j = 0; j < 8; ++j) {
                float2 w = Wlds[dk][tc + j * 32];
#pragma unroll
                for (int i = 0; i < 4; ++i)
                    acc[i][j] = fmaf(xqq[i], w.x, fmaf(xvv[i], w.y, acc[i][j]));
            }
        }
    }

    // ---- epilogue: dist_sq = acc + c2[k]; weighted row softmax ----
    float c2v[8], dssv[8];
#pragma unroll
    for (int j = 0; j < 8; ++j) {
        c2v[j] = c2g[tc + j * 32];
        dssv[j] = dssg[tc + j * 32];
    }
#pragma unroll
    for (int i = 0; i < 4; ++i) {
        float e[8];
        float m = -3.0e38f;
#pragma unroll
        for (int j = 0; j < 8; ++j) {
            e[j] = -0.5f * (acc[i][j] + c2v[j]);
            m = fmaxf(m, e[j]);
        }
#pragma unroll
        for (int msk = 1; msk <= 16; msk <<= 1) m = fmaxf(m, __shfl_xor(m, msk, 64));
        float p[8];
        float s = 0.f;
#pragma unroll
        for (int j = 0; j < 8; ++j) {
            p[j] = dssv[j] * expf(e[j] - m);
            s += p[j];
        }
#pragma unroll
        for (int msk = 1; msk <= 16; msk <<= 1) s += __shfl_xor(s, msk, 64);
        const float inv = 1.0f / s;
        const int brow = bRow + tr * 4 + i;
#pragma unroll
        for (int j = 0; j < 8; ++j)
            out[(size_t)brow * K_N + tc + j * 32] = p[j] * inv;
    }
}

extern "C" void kernel_launch(void* const* d_in, const int* in_sizes, int n_in,
                              void* d_out, int out_size, void* d_ws, size_t ws_size,
                              hipStream_t stream) {
    const float* x = (const float*)d_in[0];
    const float* cen = (const float*)d_in[1];
    const float* Dm = (const float*)d_in[2];
    float* out = (float*)d_out;

    float* wsf = (float*)d_ws;
    float* W1 = wsf;                   // 256*1024 floats
    float* W2n = wsf + 262144;         // 256*1024 floats
    float* c2 = wsf + 524288;          // 256
    float* dsf = wsf + 524544;         // 256
    float* dss = wsf + 524800;         // 256
    // total ws use: ~2.1 MB

    gmm_prep1<<<dim3(K_N), dim3(256), 0, stream>>>(Dm, cen, W1, W2n, c2, dsf);
    gmm_prep2<<<dim3(1), dim3(256), 0, stream>>>(dsf, dss);
    gmm_main<<<dim3(B_N / 32), dim3(256), 0, stream>>>(x, W1, W2n, c2, dss, out);
}

// Round 2
// 80.792 us; speedup vs baseline: 3.3046x; 3.3046x over previous
//
#include <hip/hip_runtime.h>

typedef __attribute__((ext_vector_type(8))) short bf16x8;
typedef __attribute__((ext_vector_type(4))) float f32x4;

#define B_N 8192
#define K_N 256
#define DIM_N 1024

__device__ __forceinline__ unsigned short f2bf(float v) {
    union { float f; unsigned u; } c; c.f = v;
    unsigned u = c.u;
    u += 0x7fffu + ((u >> 16) & 1u);   // RNE
    return (unsigned short)(u >> 16);
}
__device__ __forceinline__ float bf2f(unsigned short s) {
    union { unsigned u; float f; } c; c.u = ((unsigned)s) << 16;
    return c.f;
}

// ---------- prep_w1: per class k -> w2 (fp32 temp), U = bf16(Dinv-1), c2[k], dsf[k] ----------
__global__ __launch_bounds__(256) void prep_w1(const float* __restrict__ Dm,
                                               const float* __restrict__ Cm,
                                               float* __restrict__ w2,
                                               unsigned short* __restrict__ U,
                                               float* __restrict__ c2,
                                               float* __restrict__ dsf) {
    const int k = blockIdx.x, t = threadIdx.x;
    const int d = t * 4;
    const float4 dv = *(const float4*)(Dm + k * DIM_N + d);
    const float4 cv = *(const float4*)(Cm + k * DIM_N + d);
    float dd[4] = {dv.x, dv.y, dv.z, dv.w};
    float cc[4] = {cv.x, cv.y, cv.z, cv.w};
    float w2o[4];
    unsigned short uo[4];
    float llog = 0.f, lc2 = 0.f;
#pragma unroll
    for (int i = 0; i < 4; ++i) {
        float da = fabsf(dd[i]) + 1e-4f;
        float dinv = 1.0f / da;
        llog += logf(da);
        lc2 += cc[i] * cc[i] * dinv;
        uo[i] = f2bf(dinv - 1.0f);
        w2o[i] = -2.0f * cc[i] * dinv;
    }
    *(float4*)(w2 + (size_t)k * DIM_N + d) = make_float4(w2o[0], w2o[1], w2o[2], w2o[3]);
    *(ushort4*)(U + (size_t)k * DIM_N + d) = make_ushort4(uo[0], uo[1], uo[2], uo[3]);
#pragma unroll
    for (int m = 1; m <= 32; m <<= 1) {
        llog += __shfl_xor(llog, m, 64);
        lc2 += __shfl_xor(lc2, m, 64);
    }
    __shared__ float sl[4], sc[4];
    if ((t & 63) == 0) { sl[t >> 6] = llog; sc[t >> 6] = lc2; }
    __syncthreads();
    if (t == 0) {
        dsf[k] = -0.5f * (sl[0] + sl[1] + sl[2] + sl[3]);
        c2[k] = sc[0] + sc[1] + sc[2] + sc[3];
    }
}

// ---------- prep_n: nmean[d] = mean_k w2[k][d] ----------
__global__ __launch_bounds__(256) void prep_n(const float* __restrict__ w2,
                                              float* __restrict__ nmean) {
    const int d = blockIdx.x * 256 + threadIdx.x;
    float s = 0.f;
    for (int k = 0; k < K_N; ++k) s += w2[(size_t)k * DIM_N + d];
    nmean[d] = s * (1.0f / K_N);
}

// ---------- prep_w2: eps = w2 - nmean -> EH/EL bf16 hi/lo ----------
__global__ __launch_bounds__(256) void prep_w2(const float* __restrict__ w2,
                                               const float* __restrict__ nmean,
                                               unsigned short* __restrict__ EH,
                                               unsigned short* __restrict__ EL) {
    const int k = blockIdx.x, t = threadIdx.x;
    const int d = t * 4;
    const float4 wv = *(const float4*)(w2 + (size_t)k * DIM_N + d);
    const float4 nv = *(const float4*)(nmean + d);
    float w[4] = {wv.x, wv.y, wv.z, wv.w};
    float n[4] = {nv.x, nv.y, nv.z, nv.w};
    unsigned short eh[4], el[4];
#pragma unroll
    for (int i = 0; i < 4; ++i) {
        float e = w[i] - n[i];
        eh[i] = f2bf(e);
        el[i] = f2bf(e - bf2f(eh[i]));
    }
    *(ushort4*)(EH + (size_t)k * DIM_N + d) = make_ushort4(eh[0], eh[1], eh[2], eh[3]);
    *(ushort4*)(EL + (size_t)k * DIM_N + d) = make_ushort4(el[0], el[1], el[2], el[3]);
}

// ---------- prep2: dss[k] = exp(dsf[k] - max) ----------
__global__ __launch_bounds__(256) void prep2(const float* __restrict__ dsf,
                                             float* __restrict__ dss) {
    const int t = threadIdx.x;
    const float v = dsf[t];
    float m = v;
#pragma unroll
    for (int msk = 1; msk <= 32; msk <<= 1) m = fmaxf(m, __shfl_xor(m, msk, 64));
    __shared__ float sm[4];
    if ((t & 63) == 0) sm[t >> 6] = m;
    __syncthreads();
    m = fmaxf(fmaxf(sm[0], sm[1]), fmaxf(sm[2], sm[3]));
    dss[t] = expf(v - m);
}

// ---------- main: MFMA GEMM (x^2*u + x_hi*eh + x_hi*el + x_lo*eh) + fused softmax ----------
// Block: 32 rows x 256 classes, 512 threads (8 waves). Wave w: classes w*32..w*32+31.
// Per-wave frags: 2 m (rows) x 2 n (classes) 16x16 accum tiles, K-chunks of 64.
__global__ __launch_bounds__(512) void gmm_main(const float* __restrict__ x,
                                                const unsigned short* __restrict__ U,
                                                const unsigned short* __restrict__ EH,
                                                const unsigned short* __restrict__ EL,
                                                const float* __restrict__ c2g,
                                                const float* __restrict__ dssg,
                                                float* __restrict__ out) {
    __shared__ unsigned short A2[2][2048], XH[2][2048], XL[2][2048];  // 4 KB each, dbuf
    __shared__ float red[8][32];

    const int tid = threadIdx.x;
    const int wave = tid >> 6, lane = tid & 63;
    const int l15 = lane & 15, g = lane >> 4;
    const int bRow = blockIdx.x * 32;

    const int cls0 = wave * 32 + l15;
    const size_t wrow0 = (size_t)cls0 * DIM_N + g * 8;
    const size_t wrow1 = (size_t)(cls0 + 16) * DIM_N + g * 8;

    // x staging: thread -> row = tid>>4 (0..31), 4 floats at (tid&15)*4
    const int srow = tid >> 4, sdg = tid & 15;
    const float* xp = x + (size_t)(bRow + srow) * DIM_N + sdg * 4;
    const int wbyte = (srow * 128 + sdg * 8) ^ ((srow & 7) << 4);  // swizzled LDS byte

    f32x4 acc[2][2];
#pragma unroll
    for (int m = 0; m < 2; ++m)
#pragma unroll
        for (int n = 0; n < 2; ++n) {
            f32x4 z = {0.f, 0.f, 0.f, 0.f};
            acc[m][n] = z;
        }

    auto stage_write = [&](int sel, float4 v) {
        float vv[4] = {v.x, v.y, v.z, v.w};
        unsigned short h[4], l[4], q[4];
#pragma unroll
        for (int i = 0; i < 4; ++i) {
            float f = vv[i];
            unsigned short hb = f2bf(f);
            float hf = bf2f(hb);
            h[i] = hb;
            l[i] = f2bf(f - hf);
            q[i] = f2bf(f * f);
        }
        *(ushort4*)((char*)&A2[sel][0] + wbyte) = make_ushort4(q[0], q[1], q[2], q[3]);
        *(ushort4*)((char*)&XH[sel][0] + wbyte) = make_ushort4(h[0], h[1], h[2], h[3]);
        *(ushort4*)((char*)&XL[sel][0] + wbyte) = make_ushort4(l[0], l[1], l[2], l[3]);
    };

    float4 xr[2];
    xr[0] = *(const float4*)(xp);
    xr[1] = *(const float4*)(xp + 64);
    stage_write(0, xr[0]);
    __syncthreads();

#pragma unroll
    for (int c = 0; c < 16; ++c) {
        const int d0 = c * 64;
        // ---- issue W loads for this chunk (12 x 16B from L2) ----
        bf16x8 wu[2][2], wh[2][2], wl[2][2];
#pragma unroll
        for (int dk = 0; dk < 2; ++dk) {
            wu[0][dk] = *(const bf16x8*)(U + wrow0 + d0 + dk * 32);
            wu[1][dk] = *(const bf16x8*)(U + wrow1 + d0 + dk * 32);
            wh[0][dk] = *(const bf16x8*)(EH + wrow0 + d0 + dk * 32);
            wh[1][dk] = *(const bf16x8*)(EH + wrow1 + d0 + dk * 32);
            wl[0][dk] = *(const bf16x8*)(EL + wrow0 + d0 + dk * 32);
            wl[1][dk] = *(const bf16x8*)(EL + wrow1 + d0 + dk * 32);
        }
        // ---- prefetch x for chunk c+2 into the reg just freed ----
        if (c < 14) xr[c & 1] = *(const float4*)(xp + (c + 2) * 64);
        // ---- stage chunk c+1 into the other LDS buffer ----
        if (c < 15) stage_write((c + 1) & 1, xr[(c + 1) & 1]);
        // ---- compute chunk c ----
        const int sel = c & 1;
#pragma unroll
        for (int dk = 0; dk < 2; ++dk) {
            bf16x8 a2f[2], ahf[2], alf[2];
#pragma unroll
            for (int m = 0; m < 2; ++m) {
                const int row = l15 + m * 16;
                const int rb = (row * 128 + dk * 64 + g * 16) ^ ((row & 7) << 4);
                a2f[m] = *(const bf16x8*)((const char*)&A2[sel][0] + rb);
                ahf[m] = *(const bf16x8*)((const char*)&XH[sel][0] + rb);
                alf[m] = *(const bf16x8*)((const char*)&XL[sel][0] + rb);
            }
#pragma unroll
            for (int m = 0; m < 2; ++m)
#pragma unroll
                for (int n = 0; n < 2; ++n) {
                    acc[m][n] = __builtin_amdgcn_mfma_f32_16x16x32_bf16(a2f[m], wu[n][dk], acc[m][n], 0, 0, 0);
                    acc[m][n] = __builtin_amdgcn_mfma_f32_16x16x32_bf16(ahf[m], wh[n][dk], acc[m][n], 0, 0, 0);
                    acc[m][n] = __builtin_amdgcn_mfma_f32_16x16x32_bf16(ahf[m], wl[n][dk], acc[m][n], 0, 0, 0);
                    acc[m][n] = __builtin_amdgcn_mfma_f32_16x16x32_bf16(alf[m], wh[n][dk], acc[m][n], 0, 0, 0);
                }
        }
        __syncthreads();
    }

    // ---- epilogue: expo' = -0.5*(acc + c2[k]) (differs from ref by row-const: softmax-invariant) ----
    const float c2v[2] = {c2g[cls0], c2g[cls0 + 16]};
    const float dsv[2] = {dssg[cls0], dssg[cls0 + 16]};

    float e[2][2][4];
#pragma unroll
    for (int m = 0; m < 2; ++m)
#pragma unroll
        for (int n = 0; n < 2; ++n)
#pragma unroll
            for (int j = 0; j < 4; ++j)
                e[m][n][j] = -0.5f * (acc[m][n][j] + c2v[n]);

    float mx[2][4];
#pragma unroll
    for (int m = 0; m < 2; ++m)
#pragma unroll
        for (int j = 0; j < 4; ++j) mx[m][j] = fmaxf(e[m][0][j], e[m][1][j]);
#pragma unroll
    for (int msk = 1; msk <= 8; msk <<= 1)
#pragma unroll
        for (int m = 0; m < 2; ++m)
#pragma unroll
            for (int j = 0; j < 4; ++j)
                mx[m][j] = fmaxf(mx[m][j], __shfl_xor(mx[m][j], msk, 64));
    if (l15 == 0) {
#pragma unroll
        for (int m = 0; m < 2; ++m)
#pragma unroll
            for (int j = 0; j < 4; ++j) red[wave][m * 16 + g * 4 + j] = mx[m][j];
    }
    __syncthreads();
    float gm[2][4];
#pragma unroll
    for (int m = 0; m < 2; ++m)
#pragma unroll
        for (int j = 0; j < 4; ++j) {
            const int r = m * 16 + g * 4 + j;
            float v = red[0][r];
#pragma unroll
            for (int w = 1; w < 8; ++w) v = fmaxf(v, red[w][r]);
            gm[m][j] = v;
        }
    __syncthreads();

    float p[2][2][4], sm[2][4];
#pragma unroll
    for (int m = 0; m < 2; ++m)
#pragma unroll
        for (int j = 0; j < 4; ++j) sm[m][j] = 0.f;
#pragma unroll
    for (int m = 0; m < 2; ++m)
#pragma unroll
        for (int n = 0; n < 2; ++n)
#pragma unroll
            for (int j = 0; j < 4; ++j) {
                p[m][n][j] = dsv[n] * __expf(e[m][n][j] - gm[m][j]);
                sm[m][j] += p[m][n][j];
            }
#pragma unroll
    for (int msk = 1; msk <= 8; msk <<= 1)
#pragma unroll
        for (int m = 0; m < 2; ++m)
#pragma unroll
            for (int j = 0; j < 4; ++j) sm[m][j] += __shfl_xor(sm[m][j], msk, 64);
    if (l15 == 0) {
#pragma unroll
        for (int m = 0; m < 2; ++m)
#pragma unroll
            for (int j = 0; j < 4; ++j) red[wave][m * 16 + g * 4 + j] = sm[m][j];
    }
    __syncthreads();
#pragma unroll
    for (int m = 0; m < 2; ++m)
#pragma unroll
        for (int j = 0; j < 4; ++j) {
            const int r = m * 16 + g * 4 + j;
            float t = red[0][r];
#pragma unroll
            for (int w = 1; w < 8; ++w) t += red[w][r];
            const float inv = 1.0f / t;
#pragma unroll
            for (int n = 0; n < 2; ++n)
                out[(size_t)(bRow + r) * K_N + cls0 + n * 16] = p[m][n][j] * inv;
        }
}

extern "C" void kernel_launch(void* const* d_in, const int* in_sizes, int n_in,
                              void* d_out, int out_size, void* d_ws, size_t ws_size,
                              hipStream_t stream) {
    const float* x = (const float*)d_in[0];
    const float* cen = (const float*)d_in[1];
    const float* Dm = (const float*)d_in[2];
    float* out = (float*)d_out;

    char* ws = (char*)d_ws;
    float* w2 = (float*)(ws);                       // 1 MB
    float* nmean = (float*)(ws + 1048576);          // 4 KB
    float* c2 = (float*)(ws + 1052672);             // 1 KB
    float* dsf = (float*)(ws + 1053696);            // 1 KB
    float* dss = (float*)(ws + 1054720);            // 1 KB
    unsigned short* U = (unsigned short*)(ws + 1055744);   // 512 KB
    unsigned short* EH = (unsigned short*)(ws + 1580032);  // 512 KB
    unsigned short* EL = (unsigned short*)(ws + 2104320);  // 512 KB

    prep_w1<<<dim3(K_N), dim3(256), 0, stream>>>(Dm, cen, w2, U, c2, dsf);
    prep_n<<<dim3(4), dim3(256), 0, stream>>>(w2, nmean);
    prep_w2<<<dim3(K_N), dim3(256), 0, stream>>>(w2, nmean, EH, EL);
    prep2<<<dim3(1), dim3(256), 0, stream>>>(dsf, dss);
    gmm_main<<<dim3(B_N / 32), dim3(512), 0, stream>>>(x, U, EH, EL, c2, dss, out);
}

// Round 3
// 72.669 us; speedup vs baseline: 3.6741x; 1.1118x over previous
//
#include <hip/hip_runtime.h>
#include <hip/hip_bf16.h>

typedef __attribute__((ext_vector_type(8))) short bf16x8;
typedef __attribute__((ext_vector_type(4))) float f32x4;

#define B_N 8192
#define K_N 256
#define DIM_N 1024

__device__ __forceinline__ unsigned short f2bf(float v) {
    union { __hip_bfloat16 h; unsigned short u; } c;
    c.h = __float2bfloat16(v);
    return c.u;
}
__device__ __forceinline__ float bf2f(unsigned short s) {
    union { unsigned u; float f; } c; c.u = ((unsigned)s) << 16;
    return c.f;
}

// ---------- prep_w: per class k -> U=bf16(Dinv-1), WH/WL = hi/lo bf16 of -2c*Dinv, c2[k], dsf[k] ----------
__global__ __launch_bounds__(256) void prep_w(const float* __restrict__ Dm,
                                              const float* __restrict__ Cm,
                                              unsigned short* __restrict__ U,
                                              unsigned short* __restrict__ WH,
                                              unsigned short* __restrict__ WL,
                                              float* __restrict__ c2,
                                              float* __restrict__ dsf) {
    const int k = blockIdx.x, t = threadIdx.x;
    const int d = t * 4;
    const float4 dv = *(const float4*)(Dm + (size_t)k * DIM_N + d);
    const float4 cv = *(const float4*)(Cm + (size_t)k * DIM_N + d);
    float dd[4] = {dv.x, dv.y, dv.z, dv.w};
    float cc[4] = {cv.x, cv.y, cv.z, cv.w};
    unsigned short uo[4], who[4], wlo[4];
    float llog = 0.f, lc2 = 0.f;
#pragma unroll
    for (int i = 0; i < 4; ++i) {
        float da = fabsf(dd[i]) + 1e-4f;
        float dinv = 1.0f / da;
        llog += logf(da);
        lc2 += cc[i] * cc[i] * dinv;
        uo[i] = f2bf(dinv - 1.0f);
        float w2 = -2.0f * cc[i] * dinv;
        who[i] = f2bf(w2);
        wlo[i] = f2bf(w2 - bf2f(who[i]));
    }
    *(ushort4*)(U + (size_t)k * DIM_N + d) = make_ushort4(uo[0], uo[1], uo[2], uo[3]);
    *(ushort4*)(WH + (size_t)k * DIM_N + d) = make_ushort4(who[0], who[1], who[2], who[3]);
    *(ushort4*)(WL + (size_t)k * DIM_N + d) = make_ushort4(wlo[0], wlo[1], wlo[2], wlo[3]);
#pragma unroll
    for (int m = 1; m <= 32; m <<= 1) {
        llog += __shfl_xor(llog, m, 64);
        lc2 += __shfl_xor(lc2, m, 64);
    }
    __shared__ float sl[4], sc[4];
    if ((t & 63) == 0) { sl[t >> 6] = llog; sc[t >> 6] = lc2; }
    __syncthreads();
    if (t == 0) {
        dsf[k] = -0.5f * (sl[0] + sl[1] + sl[2] + sl[3]);
        c2[k] = sc[0] + sc[1] + sc[2] + sc[3];
    }
}

// ---------- prep2: dss[k] = exp(dsf[k] - max) ----------
__global__ __launch_bounds__(256) void prep2(const float* __restrict__ dsf,
                                             float* __restrict__ dss) {
    const int t = threadIdx.x;
    const float v = dsf[t];
    float m = v;
#pragma unroll
    for (int msk = 1; msk <= 32; msk <<= 1) m = fmaxf(m, __shfl_xor(m, msk, 64));
    __shared__ float sm[4];
    if ((t & 63) == 0) sm[t >> 6] = m;
    __syncthreads();
    m = fmaxf(fmaxf(sm[0], sm[1]), fmaxf(sm[2], sm[3]));
    dss[t] = expf(v - m);
}

// ---------- gmm_gemm: 64x64 tile, 4 waves (2m x 2n), K-chunks of 64, W double-buffered in regs ----------
__global__ __launch_bounds__(256, 2)
void gmm_gemm(const float* __restrict__ x,
              const unsigned short* __restrict__ U,
              const unsigned short* __restrict__ WH,
              const unsigned short* __restrict__ WL,
              float* __restrict__ S) {
    __shared__ unsigned short A2[2][4096], XH[2][4096], XL[2][4096];  // 48 KB

    const int tid = threadIdx.x;
    const int wave = tid >> 6, lane = tid & 63;
    const int l15 = lane & 15, g = lane >> 4;
    const int wm = wave & 1, wn = wave >> 1;

    const int bRow = (int)(blockIdx.x >> 2) * 64;
    const int bCol = (int)(blockIdx.x & 3) * 64;

    const int c0 = bCol + wn * 32 + l15;
    const size_t wr0 = (size_t)c0 * DIM_N + g * 8;
    const size_t wr1 = (size_t)(c0 + 16) * DIM_N + g * 8;

    // x staging: thread -> row = tid>>2 (0..63), 16 dims at (tid&3)*16
    const int srow = tid >> 2, scg = tid & 3;
    const float* xp = x + (size_t)(bRow + srow) * DIM_N + scg * 16;
    // swizzled LDS byte offsets for the two 16B halves (slot ^= row&7)
    const int wb0 = srow * 128 + ((((scg << 1) | 0) ^ (srow & 7)) << 4);
    const int wb1 = srow * 128 + ((((scg << 1) | 1) ^ (srow & 7)) << 4);

    f32x4 acc[2][2];
#pragma unroll
    for (int m = 0; m < 2; ++m)
#pragma unroll
        for (int n = 0; n < 2; ++n) {
            f32x4 z = {0.f, 0.f, 0.f, 0.f};
            acc[m][n] = z;
        }

    float4 xr[2][4];
    bf16x8 wu[2][2][2], wh[2][2][2], wl[2][2][2];  // [bank][n][dk]

    auto loadW = [&](int bank, int c) {
        const int d0 = c * 64;
#pragma unroll
        for (int dk = 0; dk < 2; ++dk) {
            wu[bank][0][dk] = *(const bf16x8*)(U + wr0 + d0 + dk * 32);
            wu[bank][1][dk] = *(const bf16x8*)(U + wr1 + d0 + dk * 32);
            wh[bank][0][dk] = *(const bf16x8*)(WH + wr0 + d0 + dk * 32);
            wh[bank][1][dk] = *(const bf16x8*)(WH + wr1 + d0 + dk * 32);
            wl[bank][0][dk] = *(const bf16x8*)(WL + wr0 + d0 + dk * 32);
            wl[bank][1][dk] = *(const bf16x8*)(WL + wr1 + d0 + dk * 32);
        }
    };
    auto loadX = [&](int bank, int c) {
        const int d0 = c * 64;
#pragma unroll
        for (int q = 0; q < 4; ++q) xr[bank][q] = *(const float4*)(xp + d0 + q * 4);
    };
    auto stage = [&](int sel, int bank) {
        unsigned short q2[16], qh[16], ql[16];
#pragma unroll
        for (int q = 0; q < 4; ++q) {
            float vv[4] = {xr[bank][q].x, xr[bank][q].y, xr[bank][q].z, xr[bank][q].w};
#pragma unroll
            for (int i = 0; i < 4; ++i) {
                const float f = vv[i];
                const unsigned short hb = f2bf(f);
                qh[q * 4 + i] = hb;
                ql[q * 4 + i] = f2bf(f - bf2f(hb));
                q2[q * 4 + i] = f2bf(f * f);
            }
        }
        *(bf16x8*)((char*)&A2[sel][0] + wb0) = *(const bf16x8*)&q2[0];
        *(bf16x8*)((char*)&A2[sel][0] + wb1) = *(const bf16x8*)&q2[8];
        *(bf16x8*)((char*)&XH[sel][0] + wb0) = *(const bf16x8*)&qh[0];
        *(bf16x8*)((char*)&XH[sel][0] + wb1) = *(const bf16x8*)&qh[8];
        *(bf16x8*)((char*)&XL[sel][0] + wb0) = *(const bf16x8*)&ql[0];
        *(bf16x8*)((char*)&XL[sel][0] + wb1) = *(const bf16x8*)&ql[8];
    };
    auto compute = [&](int sel, int bank) {
#pragma unroll
        for (int dk = 0; dk < 2; ++dk) {
            bf16x8 a2f[2], ahf[2], alf[2];
#pragma unroll
            for (int m = 0; m < 2; ++m) {
                const int row = wm * 32 + m * 16 + l15;
                const int rb = row * 128 + (((dk * 4 + g) ^ (row & 7)) << 4);
                a2f[m] = *(const bf16x8*)((const char*)&A2[sel][0] + rb);
                ahf[m] = *(const bf16x8*)((const char*)&XH[sel][0] + rb);
                alf[m] = *(const bf16x8*)((const char*)&XL[sel][0] + rb);
            }
#pragma unroll
            for (int m = 0; m < 2; ++m)
#pragma unroll
                for (int n = 0; n < 2; ++n) {
                    acc[m][n] = __builtin_amdgcn_mfma_f32_16x16x32_bf16(a2f[m], wu[bank][n][dk], acc[m][n], 0, 0, 0);
                    acc[m][n] = __builtin_amdgcn_mfma_f32_16x16x32_bf16(ahf[m], wh[bank][n][dk], acc[m][n], 0, 0, 0);
                    acc[m][n] = __builtin_amdgcn_mfma_f32_16x16x32_bf16(ahf[m], wl[bank][n][dk], acc[m][n], 0, 0, 0);
                    acc[m][n] = __builtin_amdgcn_mfma_f32_16x16x32_bf16(alf[m], wh[bank][n][dk], acc[m][n], 0, 0, 0);
                }
        }
    };

    // prologue
    loadX(0, 0);
    loadW(0, 0);
    stage(0, 0);
    loadX(1, 1);
    __syncthreads();

#pragma unroll
    for (int c = 0; c < 16; ++c) {
        const int sel = c & 1, nb = sel ^ 1;
        if (c < 15) loadW(nb, c + 1);       // W for next chunk -> other reg bank
        if (c < 14) loadX(sel, c + 2);      // x two chunks ahead (bank (c+2)&1 == sel)
        if (c < 15) stage(nb, nb);          // stage chunk c+1 into other LDS buffer
        compute(sel, sel);
        __syncthreads();
    }

    // epilogue: store raw acc (dist minus row-consts, minus c2) to S = d_out
    const int orow = bRow + wm * 32 + g * 4;
    const int ocol = bCol + wn * 32 + l15;
#pragma unroll
    for (int m = 0; m < 2; ++m)
#pragma unroll
        for (int j = 0; j < 4; ++j) {
            float* p = S + (size_t)(orow + m * 16 + j) * K_N + ocol;
            p[0] = acc[m][0][j];
            p[16] = acc[m][1][j];
        }
}

// ---------- gmm_soft: in-place weighted row softmax over S[8192][256] ----------
__global__ __launch_bounds__(256)
void gmm_soft(float* __restrict__ S, const float* __restrict__ c2g,
              const float* __restrict__ dssg) {
    const int tid = threadIdx.x;
    const int wave = tid >> 6, lane = tid & 63;
    const int r = blockIdx.x * 4 + wave;
    const int k0 = lane * 4;
    float4 s = *(const float4*)(S + (size_t)r * K_N + k0);
    float4 cv = *(const float4*)(c2g + k0);
    float4 dv = *(const float4*)(dssg + k0);
    float e[4] = {-0.5f * (s.x + cv.x), -0.5f * (s.y + cv.y),
                  -0.5f * (s.z + cv.z), -0.5f * (s.w + cv.w)};
    float dvv[4] = {dv.x, dv.y, dv.z, dv.w};
    float m = fmaxf(fmaxf(e[0], e[1]), fmaxf(e[2], e[3]));
#pragma unroll
    for (int msk = 1; msk <= 32; msk <<= 1) m = fmaxf(m, __shfl_xor(m, msk, 64));
    float p[4], sum = 0.f;
#pragma unroll
    for (int j = 0; j < 4; ++j) {
        p[j] = dvv[j] * __expf(e[j] - m);
        sum += p[j];
    }
#pragma unroll
    for (int msk = 1; msk <= 32; msk <<= 1) sum += __shfl_xor(sum, msk, 64);
    const float inv = 1.0f / sum;
    *(float4*)(S + (size_t)r * K_N + k0) = make_float4(p[0] * inv, p[1] * inv, p[2] * inv, p[3] * inv);
}

extern "C" void kernel_launch(void* const* d_in, const int* in_sizes, int n_in,
                              void* d_out, int out_size, void* d_ws, size_t ws_size,
                              hipStream_t stream) {
    const float* x = (const float*)d_in[0];
    const float* cen = (const float*)d_in[1];
    const float* Dm = (const float*)d_in[2];
    float* out = (float*)d_out;

    char* ws = (char*)d_ws;
    unsigned short* U = (unsigned short*)(ws);              // 512 KB
    unsigned short* WH = (unsigned short*)(ws + 524288);    // 512 KB
    unsigned short* WL = (unsigned short*)(ws + 1048576);   // 512 KB
    float* c2 = (float*)(ws + 1572864);                     // 1 KB
    float* dsf = (float*)(ws + 1573888);                    // 1 KB
    float* dss = (float*)(ws + 1574912);                    // 1 KB

    prep_w<<<dim3(K_N), dim3(256), 0, stream>>>(Dm, cen, U, WH, WL, c2, dsf);
    prep2<<<dim3(1), dim3(256), 0, stream>>>(dsf, dss);
    gmm_gemm<<<dim3(512), dim3(256), 0, stream>>>(x, U, WH, WL, out);
    gmm_soft<<<dim3(B_N / 4), dim3(256), 0, stream>>>(out, c2, dss);
}

// Round 4
// 33.225 us; speedup vs baseline: 8.0359x; 2.1872x over previous
//
#include <hip/hip_runtime.h>

typedef _Float16 f16x8 __attribute__((ext_vector_type(8)));
typedef _Float16 f16x4 __attribute__((ext_vector_type(4)));
typedef float f32x4 __attribute__((ext_vector_type(4)));

#define B_N 8192
#define K_N 256
#define DIM_N 1024

// ---------------- prep_w: per class k -> Uf=f16(Dinv-1), Wf=f16(-2c*Dinv), c2[k], dsf[k] ----------------
__global__ __launch_bounds__(256) void prep_w(const float* __restrict__ Dm,
                                              const float* __restrict__ Cm,
                                              _Float16* __restrict__ Uf,
                                              _Float16* __restrict__ Wf,
                                              float* __restrict__ c2,
                                              float* __restrict__ dsf) {
    const int k = blockIdx.x, t = threadIdx.x;
    const int d = t * 4;
    const float4 dv = *(const float4*)(Dm + (size_t)k * DIM_N + d);
    const float4 cv = *(const float4*)(Cm + (size_t)k * DIM_N + d);
    float dd[4] = {dv.x, dv.y, dv.z, dv.w};
    float cc[4] = {cv.x, cv.y, cv.z, cv.w};
    f16x4 uo, wo;
    float llog = 0.f, lc2 = 0.f;
#pragma unroll
    for (int i = 0; i < 4; ++i) {
        float da = fabsf(dd[i]) + 1e-4f;
        float dinv = 1.0f / da;
        llog += logf(da);
        lc2 += cc[i] * cc[i] * dinv;
        uo[i] = (_Float16)(dinv - 1.0f);
        wo[i] = (_Float16)(-2.0f * cc[i] * dinv);
    }
    *(f16x4*)(Uf + (size_t)k * DIM_N + d) = uo;
    *(f16x4*)(Wf + (size_t)k * DIM_N + d) = wo;
#pragma unroll
    for (int m = 1; m <= 32; m <<= 1) {
        llog += __shfl_xor(llog, m, 64);
        lc2 += __shfl_xor(lc2, m, 64);
    }
    __shared__ float sl[4], sc[4];
    if ((t & 63) == 0) { sl[t >> 6] = llog; sc[t >> 6] = lc2; }
    __syncthreads();
    if (t == 0) {
        dsf[k] = -0.5f * (sl[0] + sl[1] + sl[2] + sl[3]);
        c2[k] = sc[0] + sc[1] + sc[2] + sc[3];
    }
}

// ---------------- prep2: dss[k] = exp(dsf[k] - max) ----------------
__global__ __launch_bounds__(256) void prep2(const float* __restrict__ dsf,
                                             float* __restrict__ dss) {
    const int t = threadIdx.x;
    const float v = dsf[t];
    float m = v;
#pragma unroll
    for (int msk = 1; msk <= 32; msk <<= 1) m = fmaxf(m, __shfl_xor(m, msk, 64));
    __shared__ float sm[4];
    if ((t & 63) == 0) sm[t >> 6] = m;
    __syncthreads();
    m = fmaxf(fmaxf(sm[0], sm[1]), fmaxf(sm[2], sm[3]));
    dss[t] = expf(v - m);
}

// ---------------- gmm_gemm: one product-type per block ----------------
// grid 256 = 64 row-panels x 2 col-panels x 2 types. Block: 128x128, 8 waves
// (2 wave-rows x 4 wave-cols), wave-tile 64x32 (m4 x n2 of 16x16x32 f16 MFMA).
// LDS cells: cell(i,s) = s*2048 + (i^s)*16  (i=row/col 0..127, s=k-slot 0..7).
__global__ __launch_bounds__(512, 1)
void gmm_gemm(const float* __restrict__ x,
              const _Float16* __restrict__ Uf,
              const _Float16* __restrict__ Wf,
              float* __restrict__ P0, float* __restrict__ P1) {
    __shared__ __align__(16) char lds[65536];  // A: 0,16K  B: 32K,48K

    const int tid = threadIdx.x;
    const int wave = tid >> 6, lane = tid & 63, l15 = lane & 15, g = lane >> 4;
    const int wr = wave >> 2, wc = wave & 3;

    // XCD-aware decode: the 4 blocks (2 col-panels x 2 types) of a row-panel
    // land on the same XCD (bid%8 selects XCD on dispatch).
    const int bid = blockIdx.x;
    const int xcd = bid & 7, i2 = bid >> 3;
    const int rowp = (i2 >> 2) * 8 + xcd;     // 0..63
    const int tc = i2 & 3;
    const int type = tc & 1, colp = tc >> 1;
    const int bRow = rowp * 128;
    const int bCol = colp * 128;

    const _Float16* __restrict__ Wsrc = type ? Wf : Uf;
    const bool sq = (type == 0);

    // x staging: thread -> row r_=tid>>2 (0..127), 16 dims at (tid&3)*16
    const int r_ = tid >> 2, q_ = tid & 3;
    const float* xp = x + (size_t)(bRow + r_) * DIM_N + q_ * 16;
    const _Float16* wp = Wsrc + (size_t)(bCol + r_) * DIM_N + q_ * 16;

    // LDS write offsets (two cells per thread, shared by A and B tiles)
    int cwr[2];
#pragma unroll
    for (int j = 0; j < 2; ++j) {
        const int s = q_ * 2 + j;
        cwr[j] = s * 2048 + ((r_ ^ s) & 127) * 16;
    }
    // frag read offsets
    int aRd[4][2], bRd[2][2];
#pragma unroll
    for (int k2 = 0; k2 < 2; ++k2) {
        const int s = k2 * 4 + g;
#pragma unroll
        for (int m = 0; m < 4; ++m) {
            const int row = wr * 64 + m * 16 + l15;
            aRd[m][k2] = s * 2048 + ((row ^ s) & 127) * 16;
        }
#pragma unroll
        for (int n = 0; n < 2; ++n) {
            const int col = wc * 32 + n * 16 + l15;
            bRd[n][k2] = s * 2048 + ((col ^ s) & 127) * 16;
        }
    }

    f32x4 acc[4][2];
#pragma unroll
    for (int m = 0; m < 4; ++m)
#pragma unroll
        for (int n = 0; n < 2; ++n) {
            f32x4 z = {0.f, 0.f, 0.f, 0.f};
            acc[m][n] = z;
        }

    float4 xv[2][4];   // [bank][q4]  x for chunk (bank parity)
    f16x8 wv[2][2];    // [bank][j]   W halves for chunk

    auto loadX = [&](int bank, int c) {
#pragma unroll
        for (int q = 0; q < 4; ++q) xv[bank][q] = *(const float4*)(xp + c * 64 + q * 4);
    };
    auto loadB = [&](int bank, int c) {
        wv[bank][0] = *(const f16x8*)(wp + c * 64);
        wv[bank][1] = *(const f16x8*)(wp + c * 64 + 8);
    };
    auto stage = [&](int abase, int bbase, int bank) {
        // A: convert 16 floats (optionally squared) -> 2 cells
        _Float16 h[16];
#pragma unroll
        for (int q = 0; q < 4; ++q) {
            float f4[4] = {xv[bank][q].x, xv[bank][q].y, xv[bank][q].z, xv[bank][q].w};
#pragma unroll
            for (int i = 0; i < 4; ++i) {
                const float f = f4[i];
                const float t2 = sq ? f : 1.0f;
                h[q * 4 + i] = (_Float16)(f * t2);
            }
        }
        *(f16x8*)(lds + abase + cwr[0]) = *(const f16x8*)&h[0];
        *(f16x8*)(lds + abase + cwr[1]) = *(const f16x8*)&h[8];
        // B: straight f16 copy
        *(f16x8*)(lds + bbase + cwr[0]) = wv[bank][0];
        *(f16x8*)(lds + bbase + cwr[1]) = wv[bank][1];
    };

    // ---- prologue: chunks 0,1 in flight; stage chunk 0 ----
    loadX(0, 0); loadB(0, 0);
    loadX(1, 1); loadB(1, 1);
    stage(0, 32768, 0);
    asm volatile("s_waitcnt lgkmcnt(0)" ::: "memory");
    __builtin_amdgcn_s_barrier();
    __builtin_amdgcn_sched_barrier(0);

#pragma unroll
    for (int c = 0; c < 16; ++c) {
        const int cur = c & 1, nxt = cur ^ 1;
        const int aCur = cur * 16384, aNxt = nxt * 16384;
        const int bCur = 32768 + cur * 16384, bNxt = 32768 + nxt * 16384;
        // issue loads for chunk c+2 (stay in flight across the barrier)
        if (c < 14) { loadX(cur, c + 2); loadB(cur, c + 2); }
        // frags of chunk c
        f16x8 af[4][2], bf[2][2];
#pragma unroll
        for (int k2 = 0; k2 < 2; ++k2) {
#pragma unroll
            for (int m = 0; m < 4; ++m) af[m][k2] = *(const f16x8*)(lds + aCur + aRd[m][k2]);
#pragma unroll
            for (int n = 0; n < 2; ++n) bf[n][k2] = *(const f16x8*)(lds + bCur + bRd[n][k2]);
        }
        __builtin_amdgcn_s_setprio(1);
#pragma unroll
        for (int m = 0; m < 4; ++m)
#pragma unroll
            for (int n = 0; n < 2; ++n)
#pragma unroll
                for (int k2 = 0; k2 < 2; ++k2)
                    acc[m][n] = __builtin_amdgcn_mfma_f32_16x16x32_f16(af[m][k2], bf[n][k2], acc[m][n], 0, 0, 0);
        __builtin_amdgcn_s_setprio(0);
        // stage chunk c+1 into the other buffers, then barrier (no vmcnt drain)
        if (c < 15) {
            stage(aNxt, bNxt, nxt);
            asm volatile("s_waitcnt lgkmcnt(0)" ::: "memory");
            __builtin_amdgcn_s_barrier();
            __builtin_amdgcn_sched_barrier(0);
        }
    }

    // ---- epilogue: store raw partial ----
    float* __restrict__ P = type ? P1 : P0;
#pragma unroll
    for (int m = 0; m < 4; ++m) {
        const int rb = bRow + wr * 64 + m * 16 + g * 4;
        const int cb = bCol + wc * 32 + l15;
#pragma unroll
        for (int j = 0; j < 4; ++j) {
            float* p = P + (size_t)(rb + j) * K_N + cb;
            p[0] = acc[m][0][j];
            p[16] = acc[m][1][j];
        }
    }
}

// ---------------- gmm_soft: out = softmax_w(-0.5*(P0+P1+c2)) ----------------
__global__ __launch_bounds__(256)
void gmm_soft(float* __restrict__ S, const float* __restrict__ P1,
              const float* __restrict__ c2g, const float* __restrict__ dssg) {
    const int tid = threadIdx.x;
    const int wave = tid >> 6, lane = tid & 63;
    const int r = blockIdx.x * 4 + wave;
    const int k0 = lane * 4;
    float4 s0 = *(const float4*)(S + (size_t)r * K_N + k0);
    float4 s1 = *(const float4*)(P1 + (size_t)r * K_N + k0);
    float4 cv = *(const float4*)(c2g + k0);
    float4 dv = *(const float4*)(dssg + k0);
    float e[4] = {-0.5f * (s0.x + s1.x + cv.x), -0.5f * (s0.y + s1.y + cv.y),
                  -0.5f * (s0.z + s1.z + cv.z), -0.5f * (s0.w + s1.w + cv.w)};
    float dvv[4] = {dv.x, dv.y, dv.z, dv.w};
    float m = fmaxf(fmaxf(e[0], e[1]), fmaxf(e[2], e[3]));
#pragma unroll
    for (int msk = 1; msk <= 32; msk <<= 1) m = fmaxf(m, __shfl_xor(m, msk, 64));
    float p[4], sum = 0.f;
#pragma unroll
    for (int j = 0; j < 4; ++j) {
        p[j] = dvv[j] * __expf(e[j] - m);
        sum += p[j];
    }
#pragma unroll
    for (int msk = 1; msk <= 32; msk <<= 1) sum += __shfl_xor(sum, msk, 64);
    const float inv = 1.0f / sum;
    *(float4*)(S + (size_t)r * K_N + k0) = make_float4(p[0] * inv, p[1] * inv, p[2] * inv, p[3] * inv);
}

extern "C" void kernel_launch(void* const* d_in, const int* in_sizes, int n_in,
                              void* d_out, int out_size, void* d_ws, size_t ws_size,
                              hipStream_t stream) {
    const float* x = (const float*)d_in[0];
    const float* cen = (const float*)d_in[1];
    const float* Dm = (const float*)d_in[2];
    float* out = (float*)d_out;

    char* ws = (char*)d_ws;
    _Float16* Uf = (_Float16*)(ws);                 // 512 KB
    _Float16* Wf = (_Float16*)(ws + 524288);        // 512 KB
    float* P1 = (float*)(ws + 1048576);             // 8 MB
    float* c2 = (float*)(ws + 9437184);             // 1 KB
    float* dsf = (float*)(ws + 9438208);            // 1 KB
    float* dss = (float*)(ws + 9439232);            // 1 KB

    prep_w<<<dim3(K_N), dim3(256), 0, stream>>>(Dm, cen, Uf, Wf, c2, dsf);
    prep2<<<dim3(1), dim3(256), 0, stream>>>(dsf, dss);
    gmm_gemm<<<dim3(256), dim3(512), 0, stream>>>(x, Uf, Wf, out, P1);
    gmm_soft<<<dim3(B_N / 4), dim3(256), 0, stream>>>(out, P1, c2, dss);
}